// Round 1
// baseline (16360.468 us; speedup 1.0000x reference)
//
#include <hip/hip_runtime.h>

typedef unsigned short ushort_t;
typedef unsigned int u32;
typedef unsigned long long u64;
typedef __attribute__((ext_vector_type(8))) short short8;   // 8 x bf16
typedef __attribute__((ext_vector_type(4))) float floatx4;  // MFMA acc / fp32x4

#define Tt 256
#define Hh 512
#define NBLK 128
#define NBAR 64            // blocks per direction-barrier
#define NIT 258            // 256 l0 steps + 2-interval lag drain for l1
#define KCH 256
#define SLOT_SHORTS (128 * KCH)   // input-chunk slot: 128 rows x 256 k bf16 = 64KB
#define SLOT_ELEMS 65536u         // h slot: 128*512 bf16, layout [cbg32][row128][col16]
#define HS 24                     // hrep row stride (shorts), padded vs 16 for banks
#define H32S 20                   // hrep32 row stride (floats), padded vs 16
#define SMEM_BYTES (2*SLOT_SHORTS*2 + 128*HS*2 + 128*H32S*4)  // 147456

__device__ __forceinline__ float sigf(float x)  { return 1.0f / (1.0f + __expf(-x)); }
__device__ __forceinline__ float tanhf_(float x){ return 1.0f - 2.0f / (__expf(2.0f*x) + 1.0f); }

// fp32 -> bf16 RNE
__device__ __forceinline__ ushort_t f2bf(float f) {
  u32 u = __float_as_uint(f);
  u += 0x7FFFu + ((u >> 16) & 1u);
  return (ushort_t)(u >> 16);
}

// device-coherence-point accesses for cross-block h traffic (bypass the
// non-coherent per-XCD L2). Compiler-visible -> correct waitcnt insertion.
__device__ __forceinline__ u64 pload(const ushort_t* p) {
  return __hip_atomic_load((const u64*)p, __ATOMIC_RELAXED, __HIP_MEMORY_SCOPE_AGENT);
}
__device__ __forceinline__ void pstore(ushort_t* p, u64 v) {
  __hip_atomic_store((u64*)p, v, __ATOMIC_RELAXED, __HIP_MEMORY_SCOPE_AGENT);
}

// Relaxed sense-reversing barrier over NBAR blocks (one per direction).
__device__ __forceinline__ void gridbar(u32* bar) {
  __syncthreads();   // drains vmcnt/lgkmcnt per-wave before s_barrier
  if (threadIdx.x == 0) {
    asm volatile("s_waitcnt vmcnt(0)" ::: "memory");
    u32 gen = __hip_atomic_load(&bar[1], __ATOMIC_RELAXED, __HIP_MEMORY_SCOPE_AGENT);
    u32 arr = __hip_atomic_fetch_add(&bar[0], 1u, __ATOMIC_RELAXED, __HIP_MEMORY_SCOPE_AGENT);
    if (arr == NBAR - 1u) {
      __hip_atomic_store(&bar[0], 0u, __ATOMIC_RELAXED, __HIP_MEMORY_SCOPE_AGENT);
      asm volatile("s_waitcnt vmcnt(0)" ::: "memory");
      __hip_atomic_fetch_add(&bar[1], 1u, __ATOMIC_RELAXED, __HIP_MEMORY_SCOPE_AGENT);
    } else {
      while (__hip_atomic_load(&bar[1], __ATOMIC_RELAXED, __HIP_MEMORY_SCOPE_AGENT) == gen)
        __builtin_amdgcn_s_sleep(1);
    }
    asm volatile("" ::: "memory");
  }
  __syncthreads();
}

// ---------------------------------------------------------------------------
// Structure: register W^T, lane-local gates, register c-state; per direction
// 64 blocks (2 layers x 32 col-blocks) sharing one relaxed coherence-point
// barrier. New this round:
//  * h slots laid out [cbg32][row128][col16] -> coalesced stores (4KB panel
//    per producing block) and coalesced consumer loads.
//  * input chunks (x for l0, h0 for l1) prestaged to LDS BEFORE the barrier.
//    l1 runs at lag 2 (t = it-2) with a depth-4 h0 ring so h0[t] is a full
//    barrier old at prestage time (same 1-barrier invariant as before; ring
//    WAR distance >= 2 barriers).
//  * own-h (k 512..1023) skips LDS: batched pload pairs feed MFMA fragments
//    directly, double-buffered (fA/fB) so ~16-32 loads stay in flight.
// Summation order over k unchanged -> bitwise-identical math.
// ---------------------------------------------------------------------------
__global__ __launch_bounds__(128, 1) void bilstm_scan(
    const float* __restrict__ x,     // [128][256][512] fp32
    const float* __restrict__ Wx,    // [2][2][512][2048] fp32
    const float* __restrict__ Wh,    // [2][2][512][2048] fp32
    const float* __restrict__ bias,  // [2][2][2048] fp32
    ushort_t* __restrict__ ping,     // 12 h slots (zeroed by memset)
    u32* __restrict__ barws,         // barrier words (zeroed by memset)
    float* __restrict__ out)         // [128][256][1024] fp32
{
  extern __shared__ __align__(16) char smem[];
  short* actb = (short*)smem;                                   // 2 x 64 KB input slots
  ushort_t* hrep = (ushort_t*)(smem + 2 * SLOT_SHORTS * 2);     // 128 x HS bf16
  float* hrep32 = (float*)(smem + 2 * SLOT_SHORTS * 2 + 128 * HS * 2);  // 128 x H32S f32

  const int blk = blockIdx.x;
  const int chain = blk >> 5, cb = blk & 31;
  const int d = chain >> 1, l = chain & 1;
  const int tid = threadIdx.x;
  const int wv = tid >> 6, lane = tid & 63;
  const int q = lane >> 4, ln = lane & 15;
  u32* bar = barws + d * 16;  // per-direction barrier, 64 B apart
  // per-direction h slots: ring[0..3] = l0 output (ring depth 4, doubles as
  // l0's own recurrence ping), [4..5] = l1 own recurrence ping-pong.
  ushort_t* dbase = ping + (size_t)d * 6 * SLOT_ELEMS;

  // zero LDS (staging holes -> finite-wrong, never NaN)
  for (int i = tid; i < (int)(SMEM_BYTES / 4); i += 128) ((u32*)smem)[i] = 0u;
  __syncthreads();

  // ---- W^T into registers (once), fp32 -> bf16. A-row ln of tile
  // mt=wv*2+mi -> gate-col (ln&3)*512 + cb*16 + mt*4 + (ln>>2); k=kc*32+q*8+j.
  short8 wreg[2][32];
  {
    const float* wxb = Wx + (size_t)(l * 2 + d) * 512 * 2048;
    const float* whb = Wh + (size_t)(l * 2 + d) * 512 * 2048;
#pragma unroll
    for (int mi = 0; mi < 2; ++mi) {
      const int m = wv * 2 + mi;
      const int col = (ln & 3) * 512 + cb * 16 + m * 4 + (ln >> 2);
#pragma unroll
      for (int kc = 0; kc < 32; ++kc) {
        union { short8 v; ushort_t u[8]; } tmp;
#pragma unroll
        for (int j2 = 0; j2 < 8; ++j2) {
          const int k = kc * 32 + q * 8 + j2;
          const float wv_ = (k < 512) ? wxb[(size_t)k * 2048 + col]
                                      : whb[(size_t)(k - 512) * 2048 + col];
          tmp.u[j2] = f2bf(wv_);
        }
        wreg[mi][kc] = tmp.v;
      }
    }
  }

  float brs[2][4];
  {
    const float* bp = bias + (size_t)(l * 2 + d) * 2048;
#pragma unroll
    for (int mi = 0; mi < 2; ++mi) {
      const int j = cb * 16 + (wv * 2 + mi) * 4 + q;
#pragma unroll
      for (int r = 0; r < 4; ++r) brs[mi][r] = bp[r * 512 + j];
    }
  }

  float cst[2][8];
#pragma unroll
  for (int a = 0; a < 2; ++a)
#pragma unroll
    for (int b2 = 0; b2 < 8; ++b2) cst[a][b2] = 0.f;

  const int rot_t = (tid >> 1) & 31;  // LDS rotation for row = tid

  for (int it = 0; it < NIT; ++it) {
    const bool act = (l == 0) ? (it < Tt) : (it >= 2);
    const int t = (l == 0) ? it : (it - 2);

    // ================= pre-barrier: prestage input chunks 0,1 ==============
    if (act) {
      if (l == 0) {
        // x[t] fp32 -> bf16, coalesced: wave loads one full 1KB row-chunk per
        // instruction (lane = 16B unit within row).
        const int tx = d ? (Tt - 1 - t) : t;
        const float* xf = x + (size_t)tx * Hh;
#pragma unroll 1
        for (int kc = 0; kc < 2; ++kc) {
          short* dst = actb + kc * SLOT_SHORTS;
          const int k0 = kc * KCH;
#pragma unroll 8
          for (int j = 0; j < 64; ++j) {
            const int r = j * 2 + wv;  // row = batch
            floatx4 f = *(const floatx4*)(xf + (size_t)r * (Tt * Hh) + k0 + lane * 4);
            union { u64 v; ushort_t us[4]; } pk;
#pragma unroll
            for (int e = 0; e < 4; ++e) pk.us[e] = f2bf(f[e]);
            const int pos = ((lane >> 1) + (j & 31)) & 31;  // rot(r) = j
            *(u64*)&dst[r * KCH + pos * 8 + (lane & 1) * 4] = pk.v;
          }
        }
      } else {
        // h0[t] from ring slot t&3 ([cbg][row][col16]); lane = row within a
        // cbg panel -> each 8-j batch is 32 coalesced loads in flight.
        const ushort_t* h0 = dbase + (size_t)(t & 3) * SLOT_ELEMS;
#pragma unroll 1
        for (int kc = 0; kc < 2; ++kc) {
          short* dst = actb + kc * SLOT_SHORTS;
#pragma unroll 1
          for (int half = 0; half < 2; ++half) {
            u64 g[8][4];
#pragma unroll
            for (int j8 = 0; j8 < 8; ++j8) {
              const int cbg = kc * 16 + half * 8 + j8;
              const ushort_t* s = h0 + ((size_t)cbg * 128 + tid) * 16;
              g[j8][0] = pload(s);     g[j8][1] = pload(s + 4);
              g[j8][2] = pload(s + 8); g[j8][3] = pload(s + 12);
            }
#pragma unroll
            for (int j8 = 0; j8 < 8; ++j8) {
              const int u0 = (half * 8 + j8) * 2;
              const int p0 = (u0 + rot_t) & 31, p1 = (u0 + 1 + rot_t) & 31;
              uint4 v0, v1;
              v0.x = (u32)g[j8][0]; v0.y = (u32)(g[j8][0] >> 32);
              v0.z = (u32)g[j8][1]; v0.w = (u32)(g[j8][1] >> 32);
              v1.x = (u32)g[j8][2]; v1.y = (u32)(g[j8][2] >> 32);
              v1.z = (u32)g[j8][3]; v1.w = (u32)(g[j8][3] >> 32);
              *(uint4*)&dst[tid * KCH + p0 * 8] = v0;
              *(uint4*)&dst[tid * KCH + p1 * 8] = v1;
            }
          }
        }
      }
    }

    gridbar(bar);

    // ================= post-barrier: compute ================================
    if (act) {
      floatx4 acc[2][8];
      {
        floatx4 z4 = {0.f, 0.f, 0.f, 0.f};
#pragma unroll
        for (int mi = 0; mi < 2; ++mi)
#pragma unroll
          for (int nt = 0; nt < 8; ++nt) acc[mi][nt] = z4;
      }

      // ---- chunks 0,1 (input) from LDS slots
#pragma unroll
      for (int kc = 0; kc < 2; ++kc) {
        const short* src = actb + kc * SLOT_SHORTS;
#pragma unroll
        for (int s = 0; s < 8; ++s) {
          short8 af[8];
#pragma unroll
          for (int nt = 0; nt < 8; ++nt) {
            const int b = nt * 16 + ln;
            const int pos = (s * 4 + q + ((b >> 1) & 31)) & 31;
            af[nt] = *(const short8*)&src[b * KCH + pos * 8];
          }
          const int kidx = kc * 8 + s;
#pragma unroll
          for (int mi = 0; mi < 2; ++mi)
#pragma unroll
            for (int nt = 0; nt < 8; ++nt)
              acc[mi][nt] = __builtin_amdgcn_mfma_f32_16x16x32_bf16(
                  wreg[mi][kidx], af[nt], acc[mi][nt], 0, 0, 0);
        }
      }

      // ---- chunks 2,3 (own h[t-1]) direct global -> MFMA fragments
      const ushort_t* hprev = (l == 0)
          ? dbase + (size_t)((t + 3) & 3) * SLOT_ELEMS      // ring slot t-1
          : dbase + (size_t)(4 + ((t + 1) & 1)) * SLOT_ELEMS;
      // fragment (s',nt): addr = hprev + s'*4096 + (q>>1)*2048 + (nt*16+ln)*16
      //                        + (q&1)*8   [shorts]; 16 s'-groups, kidx=16+s'.
      const ushort_t* hb = hprev + (q >> 1) * 2048 + ln * 16 + (q & 1) * 8;
      typedef union { u64 qd[2]; short8 s8; } frag_u;
      frag_u fA[8], fB[8];
      auto ld_grp = [&](frag_u (&dst)[8], int sidx) {
#pragma unroll
        for (int nt = 0; nt < 8; ++nt) {
          const ushort_t* p = hb + sidx * 4096 + nt * 256;
          dst[nt].qd[0] = pload(p);
          dst[nt].qd[1] = pload(p + 4);
        }
      };
      auto mm_grp = [&](frag_u (&src)[8], int kidx) {
#pragma unroll
        for (int mi = 0; mi < 2; ++mi)
#pragma unroll
          for (int nt = 0; nt < 8; ++nt)
            acc[mi][nt] = __builtin_amdgcn_mfma_f32_16x16x32_bf16(
                wreg[mi][kidx], src[nt].s8, acc[mi][nt], 0, 0, 0);
      };
      ld_grp(fA, 0);
#pragma unroll
      for (int sp = 0; sp < 8; ++sp) {
        ld_grp(fB, 2 * sp + 1);
        mm_grp(fA, 16 + 2 * sp);
        if (sp < 7) ld_grp(fA, 2 * sp + 2);
        mm_grp(fB, 16 + 2 * sp + 1);
      }

      // ---- cell math (lane-local), repack h via LDS for contiguous stores
      const int tout = d ? (Tt - 1 - t) : t;
      ushort_t* hdst = (l == 0)
          ? dbase + (size_t)(t & 3) * SLOT_ELEMS
          : dbase + (size_t)(4 + (t & 1)) * SLOT_ELEMS;
#pragma unroll
      for (int mi = 0; mi < 2; ++mi) {
        const int jj = (wv * 2 + mi) * 4 + q;
#pragma unroll
        for (int nt = 0; nt < 8; ++nt) {
          const int b = nt * 16 + ln;
          float iv = sigf  (acc[mi][nt][0] + brs[mi][0]);
          float fv = sigf  (acc[mi][nt][1] + brs[mi][1]);
          float gv = tanhf_(acc[mi][nt][2] + brs[mi][2]);
          float ov = sigf  (acc[mi][nt][3] + brs[mi][3]);
          float cv = fv * cst[mi][nt] + iv * gv;
          cst[mi][nt] = cv;
          float hv = ov * tanhf_(cv);
          hrep[b * HS + jj] = f2bf(hv);
          if (l == 1) hrep32[b * H32S + jj] = hv;
        }
      }
      __syncthreads();
      {
        const int r = tid;  // row = batch
        uint4 h0v = *(uint4*)&hrep[r * HS];
        uint4 h1v = *(uint4*)&hrep[r * HS + 8];
        // [cbg][row][col16] layout: this block's panel is contiguous 4KB.
        ushort_t* dp = hdst + (size_t)cb * 2048 + r * 16;
        pstore(dp,      ((u64)h0v.y << 32) | h0v.x);
        pstore(dp + 4,  ((u64)h0v.w << 32) | h0v.z);
        pstore(dp + 8,  ((u64)h1v.y << 32) | h1v.x);
        pstore(dp + 12, ((u64)h1v.w << 32) | h1v.z);
        if (l == 1) {
          float* op = out + ((size_t)r * Tt + tout) * 1024 + d * 512 + cb * 16;
#pragma unroll
          for (int u = 0; u < 4; ++u)
            *(floatx4*)(op + u * 4) = *(floatx4*)&hrep32[r * H32S + u * 4];
        }
      }
    }
  }
}

// ---------------------------------------------------------------------------
extern "C" void kernel_launch(void* const* d_in, const int* in_sizes, int n_in,
                              void* d_out, int out_size, void* d_ws, size_t ws_size,
                              hipStream_t stream) {
  const float* x    = (const float*)d_in[0];  // [128,256,512] fp32
  const float* Wx   = (const float*)d_in[1];  // [2,2,512,2048] fp32
  const float* Wh   = (const float*)d_in[2];  // [2,2,512,2048] fp32
  const float* bias = (const float*)d_in[3];  // [2,2,2048] fp32

  u32* bar = (u32*)d_ws;
  ushort_t* ping = (ushort_t*)((char*)d_ws + 256);

  hipFuncSetAttribute((const void*)bilstm_scan,
                      hipFuncAttributeMaxDynamicSharedMemorySize, SMEM_BYTES);

  // zero barrier words + 12 h slots (ws is poisoned each call)
  hipMemsetAsync(d_ws, 0, 256 + (size_t)12 * SLOT_ELEMS * sizeof(ushort_t), stream);

  hipLaunchKernelGGL(bilstm_scan, dim3(NBLK), dim3(128), SMEM_BYTES, stream,
                     x, Wx, Wh, bias, ping, bar, (float*)d_out);
}

// Round 2
// 15945.804 us; speedup vs baseline: 1.0260x; 1.0260x over previous
//
#include <hip/hip_runtime.h>

typedef unsigned short ushort_t;
typedef unsigned int u32;
typedef unsigned long long u64;
typedef __attribute__((ext_vector_type(8))) short short8;   // 8 x bf16
typedef __attribute__((ext_vector_type(4))) float floatx4;  // MFMA acc / fp32x4

#define Tt 256
#define Hh 512
#define NBLK 128
#define NBAR 64            // blocks per direction-barrier
#define PING_ELEMS 65536u  // 128*512 bf16 per hidden-state slot
#define KCH 256            // k per staged chunk
#define NCH 4              // 1024 / KCH
#define SLOT_SHORTS (128 * KCH)            // one LDS slot: 128 rows x 256 k bf16
#define SMEM_BYTES (2*SLOT_SHORTS*2 + 128*16*2 + 128*16*4)  // 143360

__device__ __forceinline__ float sigf(float x)  { return 1.0f / (1.0f + __expf(-x)); }
__device__ __forceinline__ float tanhf_(float x){ return 1.0f - 2.0f / (__expf(2.0f*x) + 1.0f); }

// fp32 -> bf16 RNE
__device__ __forceinline__ ushort_t f2bf(float f) {
  u32 u = __float_as_uint(f);
  u += 0x7FFFu + ((u >> 16) & 1u);
  return (ushort_t)(u >> 16);
}

// device-coherence-point accesses for cross-block h traffic (bypass the
// non-coherent per-XCD L2).
__device__ __forceinline__ u64 pload(const ushort_t* p) {
  return __hip_atomic_load((const u64*)p, __ATOMIC_RELAXED, __HIP_MEMORY_SCOPE_AGENT);
}
__device__ __forceinline__ void pstore(ushort_t* p, u64 v) {
  __hip_atomic_store((u64*)p, v, __ATOMIC_RELAXED, __HIP_MEMORY_SCOPE_AGENT);
}

// Relaxed sense-reversing barrier over NBAR blocks (one per direction).
// Arrival counter (bar[0]) and release word (bar[32]) live on DIFFERENT
// cachelines so 63 pollers don't serialize against the arrival RMWs.
__device__ __forceinline__ void gridbar(u32* bar) {
  __syncthreads();
  if (threadIdx.x == 0) {
    asm volatile("s_waitcnt vmcnt(0)" ::: "memory");  // h-stores at coh. point
    u32 gen = __hip_atomic_load(&bar[32], __ATOMIC_RELAXED, __HIP_MEMORY_SCOPE_AGENT);
    u32 arr = __hip_atomic_fetch_add(&bar[0], 1u, __ATOMIC_RELAXED, __HIP_MEMORY_SCOPE_AGENT);
    if (arr == NBAR - 1u) {
      __hip_atomic_store(&bar[0], 0u, __ATOMIC_RELAXED, __HIP_MEMORY_SCOPE_AGENT);
      asm volatile("s_waitcnt vmcnt(0)" ::: "memory");  // reset before release
      __hip_atomic_fetch_add(&bar[32], 1u, __ATOMIC_RELAXED, __HIP_MEMORY_SCOPE_AGENT);
    } else {
      while (__hip_atomic_load(&bar[32], __ATOMIC_RELAXED, __HIP_MEMORY_SCOPE_AGENT) == gen)
        __builtin_amdgcn_s_sleep(1);
    }
    asm volatile("" ::: "memory");
  }
  __syncthreads();
}

// ---------------------------------------------------------------------------
// Round-0 structure (register W^T, lane-local gates, register c-state,
// lag-1 layer pipeline, 257 intervals, post-barrier 4-chunk double-buffered
// stage/compute pipeline). Changes this round, latency-chain surgery only:
//  * h slots re-laid out [cbg32][row128][col16]: producer panel store is
//    4KB contiguous; consumer h-staging is 2 batches of 32 independent
//    coalesced 8B loads per thread per chunk (2 latency exposures vs ~8).
//  * x staging coalesced (wave reads contiguous 1KB row-chunks).
//  * barrier arrival counter / release word on separate cachelines.
// LDS chunk layout + compute identical to round-0 -> identical arithmetic.
// ---------------------------------------------------------------------------
__global__ __launch_bounds__(128, 1) void bilstm_scan(
    const float* __restrict__ x,     // [128][256][512] fp32
    const float* __restrict__ Wx,    // [2][2][512][2048] fp32
    const float* __restrict__ Wh,    // [2][2][512][2048] fp32
    const float* __restrict__ bias,  // [2][2][2048] fp32
    ushort_t* __restrict__ ping,     // 8 h slots (zeroed by memset)
    u32* __restrict__ barws,         // barrier words (zeroed by memset)
    float* __restrict__ out)         // [128][256][1024] fp32
{
  extern __shared__ __align__(16) char smem[];
  short* actb = (short*)smem;                                   // 2 x 64 KB
  ushort_t* hrep = (ushort_t*)(smem + 2 * SLOT_SHORTS * 2);     // 128x16 bf16
  float* hrep32 = (float*)(smem + 2 * SLOT_SHORTS * 2 + 4096);  // 128x16 f32

  const int blk = blockIdx.x;
  const int chain = blk >> 5, cb = blk & 31;
  const int d = chain >> 1, l = chain & 1;
  const int tid = threadIdx.x;
  const int wv = tid >> 6, lane = tid & 63;
  const int q = lane >> 4, ln = lane & 15;
  u32* bar = barws + d * 64;  // per-direction barrier block, 256 B apart

  // zero LDS (staging holes -> finite-wrong, never NaN)
  for (int i = tid; i < (int)(SMEM_BYTES / 4); i += 128) ((u32*)smem)[i] = 0u;
  __syncthreads();

  // ---- W^T into registers (once), fp32 -> bf16. A-row ln of tile
  // mt=wv*2+mi -> gate-col (ln&3)*512 + cb*16 + mt*4 + (ln>>2); k=kc*32+q*8+j.
  short8 wreg[2][32];
  {
    const float* wxb = Wx + (size_t)(l * 2 + d) * 512 * 2048;
    const float* whb = Wh + (size_t)(l * 2 + d) * 512 * 2048;
#pragma unroll
    for (int mi = 0; mi < 2; ++mi) {
      const int m = wv * 2 + mi;
      const int col = (ln & 3) * 512 + cb * 16 + m * 4 + (ln >> 2);
#pragma unroll
      for (int kc = 0; kc < 32; ++kc) {
        union { short8 v; ushort_t u[8]; } tmp;
#pragma unroll
        for (int j2 = 0; j2 < 8; ++j2) {
          const int k = kc * 32 + q * 8 + j2;
          const float wv_ = (k < 512) ? wxb[(size_t)k * 2048 + col]
                                      : whb[(size_t)(k - 512) * 2048 + col];
          tmp.u[j2] = f2bf(wv_);
        }
        wreg[mi][kc] = tmp.v;
      }
    }
  }

  float brs[2][4];
  {
    const float* bp = bias + (size_t)(l * 2 + d) * 2048;
#pragma unroll
    for (int mi = 0; mi < 2; ++mi) {
      const int j = cb * 16 + (wv * 2 + mi) * 4 + q;
#pragma unroll
      for (int r = 0; r < 4; ++r) brs[mi][r] = bp[r * 512 + j];
    }
  }

  float cst[2][8];
#pragma unroll
  for (int a = 0; a < 2; ++a)
#pragma unroll
    for (int b2 = 0; b2 < 8; ++b2) cst[a][b2] = 0.f;

  const size_t own_base = (size_t)(l ? 4 : 0) + d * 2;
  const int rot_t = (tid >> 1) & 31;  // LDS rotation for row = tid

  for (int it = 0; it <= Tt; ++it) {
    const bool active = (l == 0) ? (it < Tt) : (it >= 1);
    if (active) {
      const int t = (l == 0) ? it : (it - 1);

      const float* xf = nullptr;     // l==0: x at time tx
      const ushort_t* xh = nullptr;  // l==1: h0[t]
      if (l == 0) {
        const int tx = d ? (Tt - 1 - t) : t;
        xf = x + (size_t)tx * Hh;
      } else {
        xh = ping + (size_t)(d * 2 + ((t + 1) & 1)) * PING_ELEMS;
      }
      const ushort_t* hp = ping + (own_base + (t & 1)) * PING_ELEMS;   // own h[t-1]
      ushort_t* hdst = ping + (own_base + ((t + 1) & 1)) * PING_ELEMS; // own h[t]

      floatx4 acc[2][8];
      {
        floatx4 z4 = {0.f, 0.f, 0.f, 0.f};
#pragma unroll
        for (int mi = 0; mi < 2; ++mi)
#pragma unroll
          for (int nt = 0; nt < 8; ++nt) acc[mi][nt] = z4;
      }

      // stage 256-k chunk kc into LDS slot kc&1. LDS layout identical to
      // round-0: row r, unit u (16B) at pos=(u+rot(r))&31, rot=(r>>1)&31.
      auto stage = [&](int kc) {
        short* dst = actb + (kc & 1) * SLOT_SHORTS;
        if (l == 0 && kc < 2) {
          // x[t] fp32 -> bf16; wave reads a contiguous 1KB row-chunk per
          // instruction (lane = 16B-of-fp32 unit within row).
          const int k0 = kc * KCH;
#pragma unroll 8
          for (int j = 0; j < 64; ++j) {
            const int r = j * 2 + wv;  // row = batch; rot(r) = j&31
            floatx4 f = *(const floatx4*)(xf + (size_t)r * ((size_t)Tt * Hh) + k0 + lane * 4);
            union { u64 v; ushort_t us[4]; } pk;
#pragma unroll
            for (int e = 0; e < 4; ++e) pk.us[e] = f2bf(f[e]);
            const int pos = ((lane >> 1) + (j & 31)) & 31;
            *(u64*)&dst[r * KCH + pos * 8 + (lane & 1) * 4] = pk.v;
          }
        } else {
          // h source in [cbg][row][col16] panels; thread = row. Two batches
          // of 32 independent coalesced 8B loads, then LDS writes.
          const ushort_t* sp_ = (kc < 2) ? xh : hp;
          const int pbase = (kc < 2) ? kc * 16 : (kc - 2) * 16;
#pragma unroll 1
          for (int half = 0; half < 2; ++half) {
            u64 g[8][4];
#pragma unroll
            for (int j8 = 0; j8 < 8; ++j8) {
              const ushort_t* s = sp_ + ((size_t)(pbase + half * 8 + j8) * 128 + tid) * 16;
              g[j8][0] = pload(s);     g[j8][1] = pload(s + 4);
              g[j8][2] = pload(s + 8); g[j8][3] = pload(s + 12);
            }
#pragma unroll
            for (int j8 = 0; j8 < 8; ++j8) {
              const int u0 = (half * 8 + j8) * 2;
              const int p0 = (u0 + rot_t) & 31, p1 = (u0 + 1 + rot_t) & 31;
              uint4 v0, v1;
              v0.x = (u32)g[j8][0]; v0.y = (u32)(g[j8][0] >> 32);
              v0.z = (u32)g[j8][1]; v0.w = (u32)(g[j8][1] >> 32);
              v1.x = (u32)g[j8][2]; v1.y = (u32)(g[j8][2] >> 32);
              v1.z = (u32)g[j8][3]; v1.w = (u32)(g[j8][3] >> 32);
              *(uint4*)&dst[tid * KCH + p0 * 8] = v0;
              *(uint4*)&dst[tid * KCH + p1 * 8] = v1;
            }
          }
        }
      };

      auto compute = [&](int kc) {
        const short* src = actb + (kc & 1) * SLOT_SHORTS;
#pragma unroll
        for (int s = 0; s < 8; ++s) {
          short8 af[8];
#pragma unroll
          for (int nt = 0; nt < 8; ++nt) {
            const int b = nt * 16 + ln;
            const int pos = (s * 4 + q + ((b >> 1) & 31)) & 31;
            af[nt] = *(const short8*)&src[b * KCH + pos * 8];
          }
          const int kidx = kc * 8 + s;
#pragma unroll
          for (int mi = 0; mi < 2; ++mi)
#pragma unroll
            for (int nt = 0; nt < 8; ++nt)
              acc[mi][nt] = __builtin_amdgcn_mfma_f32_16x16x32_bf16(
                  wreg[mi][kidx], af[nt], acc[mi][nt], 0, 0, 0);
        }
      };

      stage(0);
#pragma unroll
      for (int kc = 0; kc < NCH; ++kc) {
        __syncthreads();          // chunk kc staged; other slot free
        if (kc < NCH - 1) stage(kc + 1);
        compute(kc);
      }

      // cell math (lane-local), repack h via LDS for contiguous stores
      const int tout = d ? (Tt - 1 - t) : t;
#pragma unroll
      for (int mi = 0; mi < 2; ++mi) {
        const int jj = (wv * 2 + mi) * 4 + q;
#pragma unroll
        for (int nt = 0; nt < 8; ++nt) {
          const int b = nt * 16 + ln;
          float iv = sigf  (acc[mi][nt][0] + brs[mi][0]);
          float fv = sigf  (acc[mi][nt][1] + brs[mi][1]);
          float gv = tanhf_(acc[mi][nt][2] + brs[mi][2]);
          float ov = sigf  (acc[mi][nt][3] + brs[mi][3]);
          float cv = fv * cst[mi][nt] + iv * gv;
          cst[mi][nt] = cv;
          float hv = ov * tanhf_(cv);
          hrep[b * 16 + jj] = f2bf(hv);
          if (l == 1) hrep32[b * 16 + jj] = hv;
        }
      }
      __syncthreads();
      {
        const int r = tid;  // row = batch
        uint4 h0v = *(uint4*)&hrep[r * 16];
        uint4 h1v = *(uint4*)&hrep[r * 16 + 8];
        // [cbg][row][col16]: this block's panel is contiguous 4KB.
        ushort_t* dp = hdst + (size_t)cb * 2048 + r * 16;
        pstore(dp,      ((u64)h0v.y << 32) | h0v.x);
        pstore(dp + 4,  ((u64)h0v.w << 32) | h0v.z);
        pstore(dp + 8,  ((u64)h1v.y << 32) | h1v.x);
        pstore(dp + 12, ((u64)h1v.w << 32) | h1v.z);
        if (l == 1) {
          float* op = out + ((size_t)r * Tt + tout) * 1024 + d * 512 + cb * 16;
#pragma unroll
          for (int u = 0; u < 4; ++u)
            *(floatx4*)(op + u * 4) = *(floatx4*)&hrep32[r * 16 + u * 4];
        }
      }
    }
    gridbar(bar);
  }
}

// ---------------------------------------------------------------------------
extern "C" void kernel_launch(void* const* d_in, const int* in_sizes, int n_in,
                              void* d_out, int out_size, void* d_ws, size_t ws_size,
                              hipStream_t stream) {
  const float* x    = (const float*)d_in[0];  // [128,256,512] fp32
  const float* Wx   = (const float*)d_in[1];  // [2,2,512,2048] fp32
  const float* Wh   = (const float*)d_in[2];  // [2,2,512,2048] fp32
  const float* bias = (const float*)d_in[3];  // [2,2,2048] fp32

  u32* bar = (u32*)d_ws;
  ushort_t* ping = (ushort_t*)((char*)d_ws + 1024);

  hipFuncSetAttribute((const void*)bilstm_scan,
                      hipFuncAttributeMaxDynamicSharedMemorySize, SMEM_BYTES);

  // zero barrier words + 8 h slots (ws is poisoned each call)
  hipMemsetAsync(d_ws, 0, 1024 + (size_t)8 * PING_ELEMS * sizeof(ushort_t), stream);

  hipLaunchKernelGGL(bilstm_scan, dim3(NBLK), dim3(128), SMEM_BYTES, stream,
                     x, Wx, Wh, bias, ping, bar, (float*)d_out);
}

// Round 4
// 10844.895 us; speedup vs baseline: 1.5086x; 1.4704x over previous
//
#include <hip/hip_runtime.h>

typedef unsigned short ushort_t;
typedef unsigned int u32;
typedef unsigned long long u64;
typedef __attribute__((ext_vector_type(8))) short short8;   // 8 x bf16
typedef __attribute__((ext_vector_type(4))) float floatx4;  // MFMA acc / fp32x4

#define Tt 256
#define Hh 512
#define NBLK 128
#define THREADS 512
#define NBAR 64            // blocks per direction-barrier
#define PING_ELEMS 65536u  // 128*512 bf16 per hidden-state slot
#define KCH 256            // k per staged chunk
#define SLOT_SHORTS (128 * KCH)            // one LDS slot: 128 rows x 256 k bf16
#define SMEM_BYTES (2*SLOT_SHORTS*2 + 128*16*2 + 128*16*4)  // 143360

__device__ __forceinline__ float sigf(float x)  { return 1.0f / (1.0f + __expf(-x)); }
__device__ __forceinline__ float tanhf_(float x){ return 1.0f - 2.0f / (__expf(2.0f*x) + 1.0f); }

// fp32 -> bf16 RNE
__device__ __forceinline__ ushort_t f2bf(float f) {
  u32 u = __float_as_uint(f);
  u += 0x7FFFu + ((u >> 16) & 1u);
  return (ushort_t)(u >> 16);
}

// device-coherence-point accesses for cross-block h traffic (bypass the
// non-coherent per-XCD L2). Row-strided pattern kept deliberately: 8B
// device-scope transactions spread across 64 distinct lines/LLC slices beat
// "coalesced" contiguous atomics (rounds 1-2 evidence).
__device__ __forceinline__ u64 pload(const ushort_t* p) {
  return __hip_atomic_load((const u64*)p, __ATOMIC_RELAXED, __HIP_MEMORY_SCOPE_AGENT);
}
__device__ __forceinline__ void pstore(ushort_t* p, u64 v) {
  __hip_atomic_store((u64*)p, v, __ATOMIC_RELAXED, __HIP_MEMORY_SCOPE_AGENT);
}

// Relaxed sense-reversing barrier over NBAR blocks (one per direction).
__device__ __forceinline__ void gridbar(u32* bar) {
  __syncthreads();
  if (threadIdx.x == 0) {
    asm volatile("s_waitcnt vmcnt(0)" ::: "memory");  // h-stores at coh. point
    u32 gen = __hip_atomic_load(&bar[1], __ATOMIC_RELAXED, __HIP_MEMORY_SCOPE_AGENT);
    u32 arr = __hip_atomic_fetch_add(&bar[0], 1u, __ATOMIC_RELAXED, __HIP_MEMORY_SCOPE_AGENT);
    if (arr == NBAR - 1u) {
      __hip_atomic_store(&bar[0], 0u, __ATOMIC_RELAXED, __HIP_MEMORY_SCOPE_AGENT);
      asm volatile("s_waitcnt vmcnt(0)" ::: "memory");  // reset before release
      __hip_atomic_fetch_add(&bar[1], 1u, __ATOMIC_RELAXED, __HIP_MEMORY_SCOPE_AGENT);
    } else {
      while (__hip_atomic_load(&bar[1], __ATOMIC_RELAXED, __HIP_MEMORY_SCOPE_AGENT) == gen)
        __builtin_amdgcn_s_sleep(1);
    }
    asm volatile("" ::: "memory");
  }
  __syncthreads();
}

// ---------------------------------------------------------------------------
// Round-0 structure and access patterns EXACTLY (row-strided coherence-point
// traffic, same LDS layouts/rotations, same barrier, same k-order), with the
// block widened 128 -> 512 threads (8 waves):
//  * wave w owns (m-tile mw=w&3, row-half nw=w>>2): wreg 32 short8 (128 VGPR),
//    acc[4], cst[4] per thread.
//  * staging: thread = (row rr=tid>>2, quarter qt=tid&3) -> 16 x 8B loads per
//    chunk per thread, ALL in flight at once (1 latency exposure vs ~8), and
//    8 waves/CU hide it 4x better.
//  * atomic (h) chunks use issue/commit split: loads for chunk k+1 issued
//    before compute(k), packed+written after -> exposure hides under MFMA.
//    SINGLE in-flight buffer g (lifetimes never overlap) -> -32 VGPR.
//  * __launch_bounds__(512, 2): hard 256-VGPR cap so the 8-wave block always
//    fits 1 block/CU (round-3 launch-failure suspect).
// Per-accumulator arithmetic order identical to round-0 -> identical absmax.
// ---------------------------------------------------------------------------
__global__ __launch_bounds__(THREADS, 2) void bilstm_scan(
    const float* __restrict__ x,     // [128][256][512] fp32
    const float* __restrict__ Wx,    // [2][2][512][2048] fp32
    const float* __restrict__ Wh,    // [2][2][512][2048] fp32
    const float* __restrict__ bias,  // [2][2][2048] fp32
    ushort_t* __restrict__ ping,     // 8 h slots (zeroed by memset)
    u32* __restrict__ barws,         // barrier words (zeroed by memset)
    float* __restrict__ out)         // [128][256][1024] fp32
{
  extern __shared__ __align__(16) char smem[];
  short* actb = (short*)smem;                                   // 2 x 64 KB
  ushort_t* hrep = (ushort_t*)(smem + 2 * SLOT_SHORTS * 2);     // 128x16 bf16
  float* hrep32 = (float*)(smem + 2 * SLOT_SHORTS * 2 + 4096);  // 128x16 f32

  const int blk = blockIdx.x;
  const int chain = blk >> 5, cb = blk & 31;
  const int d = chain >> 1, l = chain & 1;
  const int tid = threadIdx.x;
  const int wvi = tid >> 6, lane = tid & 63;
  const int mw = wvi & 3, nw = wvi >> 2;      // m-tile, row-half
  const int q = lane >> 4, ln = lane & 15;
  const int rr = tid >> 2, qt = tid & 3;      // staging row / quarter
  const int rot = (rr >> 1) & 31;             // LDS rotation for row rr
  u32* bar = barws + d * 16;  // per-direction barrier, 64 B apart

  // zero LDS (staging holes -> finite-wrong, never NaN)
  for (int i = tid; i < (int)(SMEM_BYTES / 4); i += THREADS) ((u32*)smem)[i] = 0u;
  __syncthreads();

  // ---- W^T into registers (once), fp32 -> bf16. A-row ln of m-tile mw ->
  // gate-col (ln&3)*512 + cb*16 + mw*4 + (ln>>2); k = kc*32 + q*8 + j.
  short8 wreg[32];
  {
    const float* wxb = Wx + (size_t)(l * 2 + d) * 512 * 2048;
    const float* whb = Wh + (size_t)(l * 2 + d) * 512 * 2048;
    const int col = (ln & 3) * 512 + cb * 16 + mw * 4 + (ln >> 2);
#pragma unroll
    for (int kc = 0; kc < 32; ++kc) {
      union { short8 v; ushort_t u[8]; } tmp;
#pragma unroll
      for (int j2 = 0; j2 < 8; ++j2) {
        const int k = kc * 32 + q * 8 + j2;
        const float wv_ = (k < 512) ? wxb[(size_t)k * 2048 + col]
                                    : whb[(size_t)(k - 512) * 2048 + col];
        tmp.u[j2] = f2bf(wv_);
      }
      wreg[kc] = tmp.v;
    }
  }

  float brs[4];
  {
    const float* bp = bias + (size_t)(l * 2 + d) * 2048;
    const int j = cb * 16 + mw * 4 + q;
#pragma unroll
    for (int r = 0; r < 4; ++r) brs[r] = bp[r * 512 + j];
  }

  float cst[4];
#pragma unroll
  for (int b2 = 0; b2 < 4; ++b2) cst[b2] = 0.f;

  const size_t own_base = (size_t)(l ? 4 : 0) + d * 2;

  for (int it = 0; it <= Tt; ++it) {
    const bool active = (l == 0) ? (it < Tt) : (it >= 1);
    if (active) {
      const int t = (l == 0) ? it : (it - 1);

      const float* xf = nullptr;     // l==0: x at time tx
      const ushort_t* xh = nullptr;  // l==1: h0[t]
      if (l == 0) {
        const int tx = d ? (Tt - 1 - t) : t;
        xf = x + (size_t)tx * Hh;
      } else {
        xh = ping + (size_t)(d * 2 + ((t + 1) & 1)) * PING_ELEMS;
      }
      const ushort_t* hp = ping + (own_base + (t & 1)) * PING_ELEMS;   // own h[t-1]
      ushort_t* hdst = ping + (own_base + ((t + 1) & 1)) * PING_ELEMS; // own h[t]

      floatx4 acc[4];
      {
        floatx4 z4 = {0.f, 0.f, 0.f, 0.f};
#pragma unroll
        for (int nt = 0; nt < 4; ++nt) acc[nt] = z4;
      }

      // ---- staging helpers (round-0 LDS layout: row rr, 16B unit u at
      // pos=(u+rot)&31; thread covers units qt*8 .. qt*8+7).
      u64 g[8][2];

      auto h_issue = [&](const ushort_t* base, int kcol) {
        const ushort_t* s = base + (size_t)rr * Hh + kcol + qt * 64;
#pragma unroll
        for (int uu = 0; uu < 8; ++uu) {
          g[uu][0] = pload(s + uu * 8);
          g[uu][1] = pload(s + uu * 8 + 4);
        }
      };
      auto h_commit = [&](int kc) {
        short* dst = actb + (kc & 1) * SLOT_SHORTS;
#pragma unroll
        for (int uu = 0; uu < 8; ++uu) {
          uint4 v;
          v.x = (u32)g[uu][0]; v.y = (u32)(g[uu][0] >> 32);
          v.z = (u32)g[uu][1]; v.w = (u32)(g[uu][1] >> 32);
          const int pos = (qt * 8 + uu + rot) & 31;
          *(uint4*)&dst[rr * KCH + pos * 8] = v;
        }
      };
      auto x_stage = [&](int kc) {  // l==0 chunks 0,1: cached fp32 loads
        short* dst = actb + (kc & 1) * SLOT_SHORTS;
        const float* s = xf + (size_t)rr * ((size_t)Tt * Hh) + kc * KCH + qt * 64;
#pragma unroll
        for (int uu = 0; uu < 8; ++uu) {
          floatx4 f0 = *(const floatx4*)(s + uu * 8);
          floatx4 f1 = *(const floatx4*)(s + uu * 8 + 4);
          union { uint4 v; ushort_t us[8]; } pk;
#pragma unroll
          for (int e = 0; e < 4; ++e) {
            pk.us[e] = f2bf(f0[e]);
            pk.us[4 + e] = f2bf(f1[e]);
          }
          const int pos = (qt * 8 + uu + rot) & 31;
          *(uint4*)&dst[rr * KCH + pos * 8] = pk.v;
        }
      };

      auto compute = [&](int kc) {
        const short* src = actb + (kc & 1) * SLOT_SHORTS;
#pragma unroll
        for (int s = 0; s < 8; ++s) {
          short8 af[4];
#pragma unroll
          for (int nt = 0; nt < 4; ++nt) {
            const int b = nw * 64 + nt * 16 + ln;
            const int pos = (s * 4 + q + ((b >> 1) & 31)) & 31;
            af[nt] = *(const short8*)&src[b * KCH + pos * 8];
          }
          const int kidx = kc * 8 + s;
#pragma unroll
          for (int nt = 0; nt < 4; ++nt)
            acc[nt] = __builtin_amdgcn_mfma_f32_16x16x32_bf16(
                wreg[kidx], af[nt], acc[nt], 0, 0, 0);
        }
      };

      // ---- 4-chunk pipeline, issue-early / commit-late for atomic chunks.
      // Single g buffer: lifetimes are strictly sequential in both schedules.
      if (l == 0) {
        x_stage(0);
        __syncthreads();                    // slot0 = c0 ready
        h_issue(hp, 0);                     // c2 loads in flight
        x_stage(1);
        compute(0);
        __syncthreads();                    // slot1 = c1 ready
        h_commit(2);
        h_issue(hp, 256);                   // c3 loads in flight
        compute(1);
        __syncthreads();                    // slot0 = c2 ready
        h_commit(3);
        compute(2);
        __syncthreads();                    // slot1 = c3 ready
        compute(3);
      } else {
        h_issue(xh, 0);
        h_commit(0);
        h_issue(xh, 256);
        __syncthreads();                    // slot0 = c0 ready
        h_commit(1);
        h_issue(hp, 0);                     // c2 loads in flight
        compute(0);
        __syncthreads();                    // slot1 = c1 ready
        h_commit(2);
        h_issue(hp, 256);                   // c3 loads in flight
        compute(1);
        __syncthreads();                    // slot0 = c2 ready
        h_commit(3);
        compute(2);
        __syncthreads();                    // slot1 = c3 ready
        compute(3);
      }

      // ---- cell math (lane-local), repack h via LDS for contiguous stores
      const int tout = d ? (Tt - 1 - t) : t;
      const int jj = mw * 4 + q;
#pragma unroll
      for (int nt = 0; nt < 4; ++nt) {
        const int b = nw * 64 + nt * 16 + ln;
        float iv = sigf  (acc[nt][0] + brs[0]);
        float fv = sigf  (acc[nt][1] + brs[1]);
        float gv = tanhf_(acc[nt][2] + brs[2]);
        float ov = sigf  (acc[nt][3] + brs[3]);
        float cv = fv * cst[nt] + iv * gv;
        cst[nt] = cv;
        float hv = ov * tanhf_(cv);
        hrep[b * 16 + jj] = f2bf(hv);
        if (l == 1) hrep32[b * 16 + jj] = hv;
      }
      __syncthreads();
      {
        // thread (rr, qt=seg): 8B h store + 16B out store, round-0 addresses
        u64 hv64 = *(const u64*)&hrep[rr * 16 + qt * 4];
        ushort_t* dp = hdst + (size_t)rr * Hh + cb * 16 + qt * 4;
        pstore(dp, hv64);
        if (l == 1) {
          float* op = out + ((size_t)rr * Tt + tout) * 1024 + d * 512 + cb * 16 + qt * 4;
          *(floatx4*)op = *(const floatx4*)&hrep32[rr * 16 + qt * 4];
        }
      }
    }
    gridbar(bar);
  }
}

// ---------------------------------------------------------------------------
extern "C" void kernel_launch(void* const* d_in, const int* in_sizes, int n_in,
                              void* d_out, int out_size, void* d_ws, size_t ws_size,
                              hipStream_t stream) {
  const float* x    = (const float*)d_in[0];  // [128,256,512] fp32
  const float* Wx   = (const float*)d_in[1];  // [2,2,512,2048] fp32
  const float* Wh   = (const float*)d_in[2];  // [2,2,512,2048] fp32
  const float* bias = (const float*)d_in[3];  // [2,2,2048] fp32

  u32* bar = (u32*)d_ws;
  ushort_t* ping = (ushort_t*)((char*)d_ws + 256);

  hipFuncSetAttribute((const void*)bilstm_scan,
                      hipFuncAttributeMaxDynamicSharedMemorySize, SMEM_BYTES);

  // zero barrier words + 8 h slots (ws is poisoned each call)
  hipMemsetAsync(d_ws, 0, 256 + (size_t)8 * PING_ELEMS * sizeof(ushort_t), stream);

  hipLaunchKernelGGL(bilstm_scan, dim3(NBLK), dim3(THREADS), SMEM_BYTES, stream,
                     x, Wx, Wh, bias, ping, bar, (float*)d_out);
}

// Round 5
// 3949.607 us; speedup vs baseline: 4.1423x; 2.7458x over previous
//
#include <hip/hip_runtime.h>

typedef unsigned short ushort_t;
typedef unsigned int u32;
typedef unsigned long long u64;
typedef __attribute__((ext_vector_type(8))) short short8;   // 8 x bf16
typedef __attribute__((ext_vector_type(4))) float floatx4;  // MFMA acc / fp32x4

#define Tt 256
#define Hh 512
#define NBLK 256
#define THREADS 512
#define RWS 64             // batch rows per block
#define PING_ELEMS 65536u  // 128*512 bf16 per hidden-state slot
#define KCH 256            // k per staged chunk
#define SLOT_SHORTS (RWS * KCH)                 // one LDS slot: 64 rows x 256 k
#define SMEM_BYTES (2*SLOT_SHORTS*2 + RWS*16*2 + RWS*16*4)  // 71680

__device__ __forceinline__ float sigf(float x)  { return 1.0f / (1.0f + __expf(-x)); }
__device__ __forceinline__ float tanhf_(float x){ return 1.0f - 2.0f / (__expf(2.0f*x) + 1.0f); }

// fp32 -> bf16 RNE
__device__ __forceinline__ ushort_t f2bf(float f) {
  u32 u = __float_as_uint(f);
  u += 0x7FFFu + ((u >> 16) & 1u);
  return (ushort_t)(u >> 16);
}

// device-coherence-point accesses for cross-block h traffic (bypass the
// non-coherent per-XCD L2). Row-strided dispersion kept (rounds 1-2 evidence).
__device__ __forceinline__ u64 pload(const ushort_t* p) {
  return __hip_atomic_load((const u64*)p, __ATOMIC_RELAXED, __HIP_MEMORY_SCOPE_AGENT);
}
__device__ __forceinline__ void pstore(ushort_t* p, u64 v) {
  __hip_atomic_store((u64*)p, v, __ATOMIC_RELAXED, __HIP_MEMORY_SCOPE_AGENT);
}
__device__ __forceinline__ u32 aload32(const u32* p) {
  return __hip_atomic_load(p, __ATOMIC_RELAXED, __HIP_MEMORY_SCOPE_AGENT);
}
__device__ __forceinline__ void astore32(u32* p, u32 v) {
  __hip_atomic_store(p, v, __ATOMIC_RELAXED, __HIP_MEMORY_SCOPE_AGENT);
}

// ---------------------------------------------------------------------------
// Flag-array epoch barrier, one per direction (128 blocks each).
// Arrival = independent store of epoch to this block's own cacheline (no RMW
// serialization). Aggregator block's wave 0 polls all 128 flags in parallel
// (two loads/lane, __all), then publishes gen=epoch; others poll gen.
// Visibility: every wave's h pstores are drained (vmcnt0) by __syncthreads
// before the flag store; all data is at the LLC coherence point before gen.
// ---------------------------------------------------------------------------
__device__ __forceinline__ void gridbar(u32* gen, u32* flags, int fi, bool agg,
                                        u32 target) {
  __syncthreads();
  const int tid = threadIdx.x;
  if (agg) {
    if (tid < 64) {
      if (tid == 0) {
        asm volatile("s_waitcnt vmcnt(0)" ::: "memory");
        astore32(flags + fi * 16, target);
      }
      for (;;) {
        u32 a = aload32(flags + tid * 16);
        u32 b = aload32(flags + (tid + 64) * 16);
        if (__all((int)(a >= target && b >= target))) break;
        __builtin_amdgcn_s_sleep(1);
      }
      if (tid == 0) astore32(gen, target);
    }
  } else if (tid == 0) {
    asm volatile("s_waitcnt vmcnt(0)" ::: "memory");
    astore32(flags + fi * 16, target);
    while (aload32(gen) < target) __builtin_amdgcn_s_sleep(1);
  }
  asm volatile("" ::: "memory");
  __syncthreads();
}

// ---------------------------------------------------------------------------
// Round-4 structure (register W^T, lane-local gates, register c-state, lag-1
// layer pipeline, 4-chunk issue/commit staging, same LDS layout/rotation and
// per-accumulator k-order -> identical absmax). Changes this round:
//  * 256 blocks: row-split nb (64 rows each) -> ALL 256 CUs busy; per-CU LDS
//    traffic, MFMA, staging all halve (problem is fully row-separable).
//  * flag-array epoch barrier (above) replaces 64-serialized-RMW barrier.
//  * both own-h chunks' loads issued at interval top (gA/gB buffers).
// ---------------------------------------------------------------------------
__global__ __launch_bounds__(THREADS, 2) void bilstm_scan(
    const float* __restrict__ x,     // [128][256][512] fp32
    const float* __restrict__ Wx,    // [2][2][512][2048] fp32
    const float* __restrict__ Wh,    // [2][2][512][2048] fp32
    const float* __restrict__ bias,  // [2][2][2048] fp32
    ushort_t* __restrict__ ping,     // 8 h slots (zeroed by memset)
    u32* __restrict__ barws,         // gen words + flag array (zeroed)
    float* __restrict__ out)         // [128][256][1024] fp32
{
  extern __shared__ __align__(16) char smem[];
  short* actb = (short*)smem;                                   // 2 x 32 KB
  ushort_t* hrep = (ushort_t*)(smem + 2 * SLOT_SHORTS * 2);     // 64x16 bf16
  float* hrep32 = (float*)(smem + 2 * SLOT_SHORTS * 2 + RWS*16*2);  // 64x16 f32

  const int blk = blockIdx.x;
  const int cb = blk & 31, nb = (blk >> 5) & 1, l = (blk >> 6) & 1, d = blk >> 7;
  const int rb0 = nb * RWS;
  const int fi = blk & 127;            // flag index within direction
  const bool agg = (fi == 0);
  const int tid = threadIdx.x;
  const int wvi = tid >> 6, lane = tid & 63;
  const int mw = wvi & 3, nw = wvi >> 2;      // m-tile, row-half (of 64)
  const int q = lane >> 4, ln = lane & 15;
  const int rl = tid >> 3, et = tid & 7;      // staging row (0..63) / eighth
  const int rot = (rl >> 1) & 31;             // LDS rotation for local row rl
  u32* gen = barws + d * 16;                           // own 64B line
  u32* flags = barws + 64 + d * 2048;                  // 128 x 64B lines

  // zero LDS (staging holes -> finite-wrong, never NaN)
  for (int i = tid; i < (int)(SMEM_BYTES / 4); i += THREADS) ((u32*)smem)[i] = 0u;
  __syncthreads();

  // ---- W^T into registers (once), fp32 -> bf16. A-row ln of m-tile mw ->
  // gate-col (ln&3)*512 + cb*16 + mw*4 + (ln>>2); k = kc*32 + q*8 + j.
  short8 wreg[32];
  {
    const float* wxb = Wx + (size_t)(l * 2 + d) * 512 * 2048;
    const float* whb = Wh + (size_t)(l * 2 + d) * 512 * 2048;
    const int col = (ln & 3) * 512 + cb * 16 + mw * 4 + (ln >> 2);
#pragma unroll
    for (int kc = 0; kc < 32; ++kc) {
      union { short8 v; ushort_t u[8]; } tmp;
#pragma unroll
      for (int j2 = 0; j2 < 8; ++j2) {
        const int k = kc * 32 + q * 8 + j2;
        const float wv_ = (k < 512) ? wxb[(size_t)k * 2048 + col]
                                    : whb[(size_t)(k - 512) * 2048 + col];
        tmp.u[j2] = f2bf(wv_);
      }
      wreg[kc] = tmp.v;
    }
  }

  float brs[4];
  {
    const float* bp = bias + (size_t)(l * 2 + d) * 2048;
    const int j = cb * 16 + mw * 4 + q;
#pragma unroll
    for (int r = 0; r < 4; ++r) brs[r] = bp[r * 512 + j];
  }

  float cst[2];
  cst[0] = 0.f; cst[1] = 0.f;

  const size_t own_base = (size_t)(l ? 4 : 0) + d * 2;

  for (int it = 0; it <= Tt; ++it) {
    const bool active = (l == 0) ? (it < Tt) : (it >= 1);
    if (active) {
      const int t = (l == 0) ? it : (it - 1);

      const float* xf = nullptr;     // l==0: x at time tx
      const ushort_t* xh = nullptr;  // l==1: h0[t]
      if (l == 0) {
        const int tx = d ? (Tt - 1 - t) : t;
        xf = x + (size_t)tx * Hh;
      } else {
        xh = ping + (size_t)(d * 2 + ((t + 1) & 1)) * PING_ELEMS;
      }
      const ushort_t* hp = ping + (own_base + (t & 1)) * PING_ELEMS;   // own h[t-1]
      ushort_t* hdst = ping + (own_base + ((t + 1) & 1)) * PING_ELEMS; // own h[t]

      floatx4 acc[2];
      {
        floatx4 z4 = {0.f, 0.f, 0.f, 0.f};
        acc[0] = z4; acc[1] = z4;
      }

      // ---- staging (LDS layout: local row rl, 16B unit u at pos=(u+rot)&31;
      // thread covers units et*4 .. et*4+3).
      u64 gA[4][2], gB[4][2];

      auto h_issue = [&](const ushort_t* base, int kcol, u64 (&g)[4][2]) {
        const ushort_t* s = base + (size_t)(rb0 + rl) * Hh + kcol + et * 32;
#pragma unroll
        for (int uu = 0; uu < 4; ++uu) {
          g[uu][0] = pload(s + uu * 8);
          g[uu][1] = pload(s + uu * 8 + 4);
        }
      };
      auto h_commit = [&](int kc, u64 (&g)[4][2]) {
        short* dst = actb + (kc & 1) * SLOT_SHORTS;
#pragma unroll
        for (int uu = 0; uu < 4; ++uu) {
          uint4 v;
          v.x = (u32)g[uu][0]; v.y = (u32)(g[uu][0] >> 32);
          v.z = (u32)g[uu][1]; v.w = (u32)(g[uu][1] >> 32);
          const int pos = (et * 4 + uu + rot) & 31;
          *(uint4*)&dst[rl * KCH + pos * 8] = v;
        }
      };
      auto x_stage = [&](int kc) {  // l==0 chunks 0,1: cached fp32 loads
        short* dst = actb + (kc & 1) * SLOT_SHORTS;
        const float* s = xf + (size_t)(rb0 + rl) * ((size_t)Tt * Hh) + kc * KCH + et * 32;
#pragma unroll
        for (int uu = 0; uu < 4; ++uu) {
          floatx4 f0 = *(const floatx4*)(s + uu * 8);
          floatx4 f1 = *(const floatx4*)(s + uu * 8 + 4);
          union { uint4 v; ushort_t us[8]; } pk;
#pragma unroll
          for (int e = 0; e < 4; ++e) {
            pk.us[e] = f2bf(f0[e]);
            pk.us[4 + e] = f2bf(f1[e]);
          }
          const int pos = (et * 4 + uu + rot) & 31;
          *(uint4*)&dst[rl * KCH + pos * 8] = pk.v;
        }
      };

      auto compute = [&](int kc) {
        const short* src = actb + (kc & 1) * SLOT_SHORTS;
#pragma unroll
        for (int s = 0; s < 8; ++s) {
          short8 af[2];
#pragma unroll
          for (int nt = 0; nt < 2; ++nt) {
            const int b = nw * 32 + nt * 16 + ln;  // local row
            const int pos = (s * 4 + q + ((b >> 1) & 31)) & 31;
            af[nt] = *(const short8*)&src[b * KCH + pos * 8];
          }
          const int kidx = kc * 8 + s;
#pragma unroll
          for (int nt = 0; nt < 2; ++nt)
            acc[nt] = __builtin_amdgcn_mfma_f32_16x16x32_bf16(
                wreg[kidx], af[nt], acc[nt], 0, 0, 0);
        }
      };

      // ---- 4-chunk pipeline, own-h loads issued at interval top
      if (l == 0) {
        h_issue(hp, 0, gA);
        h_issue(hp, 256, gB);
        x_stage(0);
        __syncthreads();                    // slot0 = c0 ready
        x_stage(1);
        compute(0);
        __syncthreads();                    // slot1 = c1 ready
        h_commit(2, gA);
        compute(1);
        __syncthreads();                    // slot0 = c2 ready
        h_commit(3, gB);
        compute(2);
        __syncthreads();                    // slot1 = c3 ready
        compute(3);
      } else {
        h_issue(xh, 0, gA);
        h_issue(xh, 256, gB);
        h_commit(0, gA);
        __syncthreads();                    // slot0 = c0 ready
        h_commit(1, gB);
        h_issue(hp, 0, gA);                 // c2 loads in flight
        compute(0);
        __syncthreads();                    // slot1 = c1 ready
        h_commit(2, gA);
        h_issue(hp, 256, gB);               // c3 loads in flight
        compute(1);
        __syncthreads();                    // slot0 = c2 ready
        h_commit(3, gB);
        compute(2);
        __syncthreads();                    // slot1 = c3 ready
        compute(3);
      }

      // ---- cell math (lane-local), repack h via LDS for contiguous stores
      const int tout = d ? (Tt - 1 - t) : t;
      const int jj = mw * 4 + q;
#pragma unroll
      for (int nt = 0; nt < 2; ++nt) {
        const int b = nw * 32 + nt * 16 + ln;  // local row
        float iv = sigf  (acc[nt][0] + brs[0]);
        float fv = sigf  (acc[nt][1] + brs[1]);
        float gv = tanhf_(acc[nt][2] + brs[2]);
        float ov = sigf  (acc[nt][3] + brs[3]);
        float cv = fv * cst[nt] + iv * gv;
        cst[nt] = cv;
        float hv = ov * tanhf_(cv);
        hrep[b * 16 + jj] = f2bf(hv);
        if (l == 1) hrep32[b * 16 + jj] = hv;
      }
      __syncthreads();
      if (tid < 256) {
        // thread (rr 0..63, qt): 8B h store + 16B out store
        const int rr = tid >> 2, qt = tid & 3;
        u64 hv64 = *(const u64*)&hrep[rr * 16 + qt * 4];
        ushort_t* dp = hdst + (size_t)(rb0 + rr) * Hh + cb * 16 + qt * 4;
        pstore(dp, hv64);
        if (l == 1) {
          float* op = out + ((size_t)(rb0 + rr) * Tt + tout) * 1024 + d * 512 + cb * 16 + qt * 4;
          *(floatx4*)op = *(const floatx4*)&hrep32[rr * 16 + qt * 4];
        }
      }
    }
    gridbar(gen, flags, fi, agg, (u32)it + 1u);
  }
}

// ---------------------------------------------------------------------------
extern "C" void kernel_launch(void* const* d_in, const int* in_sizes, int n_in,
                              void* d_out, int out_size, void* d_ws, size_t ws_size,
                              hipStream_t stream) {
  const float* x    = (const float*)d_in[0];  // [128,256,512] fp32
  const float* Wx   = (const float*)d_in[1];  // [2,2,512,2048] fp32
  const float* Wh   = (const float*)d_in[2];  // [2,2,512,2048] fp32
  const float* bias = (const float*)d_in[3];  // [2,2,2048] fp32

  u32* bar = (u32*)d_ws;
  ushort_t* ping = (ushort_t*)((char*)d_ws + 32768);

  hipFuncSetAttribute((const void*)bilstm_scan,
                      hipFuncAttributeMaxDynamicSharedMemorySize, SMEM_BYTES);

  // zero gen words + flag array + 8 h slots (ws is poisoned each call)
  hipMemsetAsync(d_ws, 0, 32768 + (size_t)8 * PING_ELEMS * sizeof(ushort_t), stream);

  hipLaunchKernelGGL(bilstm_scan, dim3(NBLK), dim3(THREADS), SMEM_BYTES, stream,
                     x, Wx, Wh, bias, ping, bar, (float*)d_out);
}

// Round 6
// 3813.309 us; speedup vs baseline: 4.2904x; 1.0357x over previous
//
#include <hip/hip_runtime.h>

typedef unsigned short ushort_t;
typedef unsigned int u32;
typedef unsigned long long u64;
typedef __attribute__((ext_vector_type(8))) short short8;   // 8 x bf16
typedef __attribute__((ext_vector_type(4))) float floatx4;  // MFMA acc / fp32x4

#define Tt 256
#define Hh 512
#define NBLK 256
#define THREADS 512
#define RWS 64             // batch rows per block
#define NIT 258            // 256 l0 steps + 2-interval lag drain for l1
#define PING_ELEMS 65536u  // 128*512 bf16 per hidden-state slot
#define KCH 256            // k per staged chunk
#define SLOT_SHORTS (RWS * KCH)                 // one LDS slot: 64 rows x 256 k
#define SMEM_BYTES (2*SLOT_SHORTS*2 + RWS*16*2 + RWS*16*4)  // 71680

__device__ __forceinline__ float sigf(float x)  { return 1.0f / (1.0f + __expf(-x)); }
__device__ __forceinline__ float tanhf_(float x){ return 1.0f - 2.0f / (__expf(2.0f*x) + 1.0f); }

// fp32 -> bf16 RNE
__device__ __forceinline__ ushort_t f2bf(float f) {
  u32 u = __float_as_uint(f);
  u += 0x7FFFu + ((u >> 16) & 1u);
  return (ushort_t)(u >> 16);
}

// device-coherence-point accesses for cross-block h traffic (bypass the
// non-coherent per-XCD L2). Row-strided dispersion kept (rounds 1-2 evidence).
__device__ __forceinline__ u64 pload(const ushort_t* p) {
  return __hip_atomic_load((const u64*)p, __ATOMIC_RELAXED, __HIP_MEMORY_SCOPE_AGENT);
}
__device__ __forceinline__ void pstore(ushort_t* p, u64 v) {
  __hip_atomic_store((u64*)p, v, __ATOMIC_RELAXED, __HIP_MEMORY_SCOPE_AGENT);
}
__device__ __forceinline__ u32 aload32(const u32* p) {
  return __hip_atomic_load(p, __ATOMIC_RELAXED, __HIP_MEMORY_SCOPE_AGENT);
}
__device__ __forceinline__ void astore32(u32* p, u32 v) {
  __hip_atomic_store(p, v, __ATOMIC_RELAXED, __HIP_MEMORY_SCOPE_AGENT);
}

// ---------------------------------------------------------------------------
// ONE-HOP flag-array epoch barrier, per direction (128 blocks each).
// Arrival = independent epoch store to own cacheline. Release = every block's
// wave 0 polls all 128 flags itself (2 flags/lane, __all) - no aggregator hop.
// Epochs are monotonic -> no reset races. h pstores drained (vmcnt 0) before
// the flag store, so all data is at the LLC coherence point before the flag.
// ---------------------------------------------------------------------------
__device__ __forceinline__ void gridbar(u32* flags, int fi, u32 target) {
  __syncthreads();   // per-wave full drain (vmcnt/lgkmcnt) before s_barrier
  const int tid = threadIdx.x;
  if (tid == 0) {
    asm volatile("s_waitcnt vmcnt(0)" ::: "memory");
    astore32(flags + fi * 16, target);
  }
  if (tid < 64) {
    for (;;) {
      u32 a = aload32(flags + tid * 16);
      u32 b = aload32(flags + (tid + 64) * 16);
      if (__all((int)(a >= target && b >= target))) break;
      __builtin_amdgcn_s_sleep(1);
    }
  }
  asm volatile("" ::: "memory");
  __syncthreads();
}

// ---------------------------------------------------------------------------
// Round-5 structure (256 blocks row-split, 8 waves, register W^T, lane-local
// gates, register c-state, row-strided coherence traffic, same LDS layout /
// rotation / per-accumulator k-order -> identical absmax). This round:
//  * chunks 0,1 (x for l0; h0 for l1) prestaged to LDS BEFORE the barrier.
//    l1 runs at lag 2 (t = it-2) with a depth-4 h0 ring, so h0[t_next] is a
//    full barrier old at prestage time (WAR distance >= 3 barriers).
//  * post-barrier path: issue own-h loads -> compute(0) immediately ->
//    commit/compute pipeline (ONE LLC exposure, overlapped with compute).
//  * 1-hop flag barrier (above) removes the aggregator hop.
// ---------------------------------------------------------------------------
__global__ __launch_bounds__(THREADS, 2) void bilstm_scan(
    const float* __restrict__ x,     // [128][256][512] fp32
    const float* __restrict__ Wx,    // [2][2][512][2048] fp32
    const float* __restrict__ Wh,    // [2][2][512][2048] fp32
    const float* __restrict__ bias,  // [2][2][2048] fp32
    ushort_t* __restrict__ ping,     // 12 h slots (zeroed by memset)
    u32* __restrict__ barws,         // flag array (zeroed)
    float* __restrict__ out)         // [128][256][1024] fp32
{
  extern __shared__ __align__(16) char smem[];
  short* actb = (short*)smem;                                   // 2 x 32 KB
  ushort_t* hrep = (ushort_t*)(smem + 2 * SLOT_SHORTS * 2);     // 64x16 bf16
  float* hrep32 = (float*)(smem + 2 * SLOT_SHORTS * 2 + RWS*16*2);  // 64x16 f32

  const int blk = blockIdx.x;
  const int cb = blk & 31, nb = (blk >> 5) & 1, l = (blk >> 6) & 1, d = blk >> 7;
  const int rb0 = nb * RWS;
  const int fi = blk & 127;            // flag index within direction
  const int tid = threadIdx.x;
  const int wvi = tid >> 6, lane = tid & 63;
  const int mw = wvi & 3, nw = wvi >> 2;      // m-tile, row-half (of 64)
  const int q = lane >> 4, ln = lane & 15;
  const int rl = tid >> 3, et = tid & 7;      // staging row (0..63) / eighth
  const int rot = (rl >> 1) & 31;             // LDS rotation for local row rl
  u32* flags = barws + 64 + d * 2048;         // 128 x 64B lines per direction
  // per-direction h slots: ring[0..3] = l0 h (depth-4; doubles as l0's own
  // recurrence source), [4..5] = l1 own recurrence ping-pong.
  ushort_t* dbase = ping + (size_t)d * 6 * PING_ELEMS;

  // zero LDS (staging holes -> finite-wrong, never NaN)
  for (int i = tid; i < (int)(SMEM_BYTES / 4); i += THREADS) ((u32*)smem)[i] = 0u;
  __syncthreads();

  // ---- W^T into registers (once), fp32 -> bf16. A-row ln of m-tile mw ->
  // gate-col (ln&3)*512 + cb*16 + mw*4 + (ln>>2); k = kc*32 + q*8 + j.
  short8 wreg[32];
  {
    const float* wxb = Wx + (size_t)(l * 2 + d) * 512 * 2048;
    const float* whb = Wh + (size_t)(l * 2 + d) * 512 * 2048;
    const int col = (ln & 3) * 512 + cb * 16 + mw * 4 + (ln >> 2);
#pragma unroll
    for (int kc = 0; kc < 32; ++kc) {
      union { short8 v; ushort_t u[8]; } tmp;
#pragma unroll
      for (int j2 = 0; j2 < 8; ++j2) {
        const int k = kc * 32 + q * 8 + j2;
        const float wv_ = (k < 512) ? wxb[(size_t)k * 2048 + col]
                                    : whb[(size_t)(k - 512) * 2048 + col];
        tmp.u[j2] = f2bf(wv_);
      }
      wreg[kc] = tmp.v;
    }
  }

  float brs[4];
  {
    const float* bp = bias + (size_t)(l * 2 + d) * 2048;
    const int j = cb * 16 + mw * 4 + q;
#pragma unroll
    for (int r = 0; r < 4; ++r) brs[r] = bp[r * 512 + j];
  }

  float cst[2];
  cst[0] = 0.f; cst[1] = 0.f;

  // ---- staging lambdas (LDS layout: local row rl, 16B unit u at
  // pos=(u+rot)&31; thread covers units et*4 .. et*4+3).
  auto x_prestage = [&](int tn) {   // l==0: stage x[tn] chunks 0,1
    const int tx = d ? (Tt - 1 - tn) : tn;
    const float* xf = x + (size_t)tx * Hh;
#pragma unroll
    for (int kc = 0; kc < 2; ++kc) {
      short* dst = actb + kc * SLOT_SHORTS;
      const float* s = xf + (size_t)(rb0 + rl) * ((size_t)Tt * Hh) + kc * KCH + et * 32;
#pragma unroll
      for (int uu = 0; uu < 4; ++uu) {
        floatx4 f0 = *(const floatx4*)(s + uu * 8);
        floatx4 f1 = *(const floatx4*)(s + uu * 8 + 4);
        union { uint4 v; ushort_t us[8]; } pk;
#pragma unroll
        for (int e = 0; e < 4; ++e) {
          pk.us[e] = f2bf(f0[e]);
          pk.us[4 + e] = f2bf(f1[e]);
        }
        const int pos = (et * 4 + uu + rot) & 31;
        *(uint4*)&dst[rl * KCH + pos * 8] = pk.v;
      }
    }
  };

  auto h0_prestage = [&](int tn) {  // l==1: stage h0[tn] chunks 0,1
    const ushort_t* h0 = dbase + (size_t)(tn & 3) * PING_ELEMS;
    const ushort_t* s = h0 + (size_t)(rb0 + rl) * Hh + et * 32;
    u64 g[8][2];
#pragma unroll
    for (int c = 0; c < 2; ++c)     // all 8 load pairs in flight at once
#pragma unroll
      for (int uu = 0; uu < 4; ++uu) {
        g[c * 4 + uu][0] = pload(s + c * 256 + uu * 8);
        g[c * 4 + uu][1] = pload(s + c * 256 + uu * 8 + 4);
      }
#pragma unroll
    for (int c = 0; c < 2; ++c) {
      short* dst = actb + c * SLOT_SHORTS;
#pragma unroll
      for (int uu = 0; uu < 4; ++uu) {
        uint4 v;
        v.x = (u32)g[c * 4 + uu][0]; v.y = (u32)(g[c * 4 + uu][0] >> 32);
        v.z = (u32)g[c * 4 + uu][1]; v.w = (u32)(g[c * 4 + uu][1] >> 32);
        const int pos = (et * 4 + uu + rot) & 31;
        *(uint4*)&dst[rl * KCH + pos * 8] = v;
      }
    }
  };

  // ---- bootstrap: prestage interval 0 (l0 only; l1 inactive until it=2)
  if (l == 0) x_prestage(0);

  for (int it = 0; it < NIT; ++it) {
    const bool active = (l == 0) ? (it < Tt) : (it >= 2);
    const int t = (l == 0) ? it : (it - 2);

    if (active) {
      // own h[t-1]: l0 from ring slot (t-1)&3; l1 from own ping-pong.
      const ushort_t* hp = (l == 0)
          ? dbase + (size_t)((t + 3) & 3) * PING_ELEMS
          : dbase + (size_t)(4 + (t & 1)) * PING_ELEMS;
      ushort_t* hdst = (l == 0)
          ? dbase + (size_t)(t & 3) * PING_ELEMS
          : dbase + (size_t)(4 + ((t + 1) & 1)) * PING_ELEMS;

      floatx4 acc[2];
      {
        floatx4 z4 = {0.f, 0.f, 0.f, 0.f};
        acc[0] = z4; acc[1] = z4;
      }

      u64 gA[4][2], gB[4][2];
      auto h_issue = [&](int kcol, u64 (&g)[4][2]) {
        const ushort_t* s = hp + (size_t)(rb0 + rl) * Hh + kcol + et * 32;
#pragma unroll
        for (int uu = 0; uu < 4; ++uu) {
          g[uu][0] = pload(s + uu * 8);
          g[uu][1] = pload(s + uu * 8 + 4);
        }
      };
      auto h_commit = [&](int kc, u64 (&g)[4][2]) {
        short* dst = actb + (kc & 1) * SLOT_SHORTS;
#pragma unroll
        for (int uu = 0; uu < 4; ++uu) {
          uint4 v;
          v.x = (u32)g[uu][0]; v.y = (u32)(g[uu][0] >> 32);
          v.z = (u32)g[uu][1]; v.w = (u32)(g[uu][1] >> 32);
          const int pos = (et * 4 + uu + rot) & 31;
          *(uint4*)&dst[rl * KCH + pos * 8] = v;
        }
      };
      auto compute = [&](int kc) {
        const short* src = actb + (kc & 1) * SLOT_SHORTS;
#pragma unroll
        for (int s = 0; s < 8; ++s) {
          short8 af[2];
#pragma unroll
          for (int nt = 0; nt < 2; ++nt) {
            const int b = nw * 32 + nt * 16 + ln;  // local row
            const int pos = (s * 4 + q + ((b >> 1) & 31)) & 31;
            af[nt] = *(const short8*)&src[b * KCH + pos * 8];
          }
          const int kidx = kc * 8 + s;
#pragma unroll
          for (int nt = 0; nt < 2; ++nt)
            acc[nt] = __builtin_amdgcn_mfma_f32_16x16x32_bf16(
                wreg[kidx], af[nt], acc[nt], 0, 0, 0);
        }
      };

      // ---- post-barrier pipeline: chunks 0,1 already in LDS (prestaged)
      h_issue(0, gA);                 // own-h loads in flight
      h_issue(256, gB);
      compute(0);
      __syncthreads();                // all done reading slot0
      h_commit(2, gA);
      compute(1);
      __syncthreads();                // slot0 committed; all done slot1 reads
      h_commit(3, gB);
      compute(2);
      __syncthreads();                // slot1 committed
      compute(3);

      // ---- cell math (lane-local), repack h via LDS for contiguous stores
      const int tout = d ? (Tt - 1 - t) : t;
      const int jj = mw * 4 + q;
#pragma unroll
      for (int nt = 0; nt < 2; ++nt) {
        const int b = nw * 32 + nt * 16 + ln;  // local row
        float iv = sigf  (acc[nt][0] + brs[0]);
        float fv = sigf  (acc[nt][1] + brs[1]);
        float gv = tanhf_(acc[nt][2] + brs[2]);
        float ov = sigf  (acc[nt][3] + brs[3]);
        float cv = fv * cst[nt] + iv * gv;
        cst[nt] = cv;
        float hv = ov * tanhf_(cv);
        hrep[b * 16 + jj] = f2bf(hv);
        if (l == 1) hrep32[b * 16 + jj] = hv;
      }
      __syncthreads();                // hrep ready; also: all slot reads done
      if (tid < 256) {
        const int rr = tid >> 2, qt = tid & 3;
        u64 hv64 = *(const u64*)&hrep[rr * 16 + qt * 4];
        ushort_t* dp = hdst + (size_t)(rb0 + rr) * Hh + cb * 16 + qt * 4;
        pstore(dp, hv64);
        if (l == 1) {
          float* op = out + ((size_t)(rb0 + rr) * Tt + tout) * 1024 + d * 512 + cb * 16 + qt * 4;
          *(floatx4*)op = *(const floatx4*)&hrep32[rr * 16 + qt * 4];
        }
      }
    }

    // ---- prestage chunks 0,1 for interval it+1 (slots free: all reads done
    // before the last __syncthreads above; gridbar orders writes for readers)
    const bool nact = (l == 0) ? (it + 1 < Tt) : (it + 1 >= 2 && it + 1 < NIT);
    if (nact) {
      if (l == 0) x_prestage(it + 1);
      else        h0_prestage(it - 1);   // t_next = (it+1)-2; ring slot (it-1)&3
    }

    gridbar(flags, fi, (u32)it + 1u);
  }
}

// ---------------------------------------------------------------------------
extern "C" void kernel_launch(void* const* d_in, const int* in_sizes, int n_in,
                              void* d_out, int out_size, void* d_ws, size_t ws_size,
                              hipStream_t stream) {
  const float* x    = (const float*)d_in[0];  // [128,256,512] fp32
  const float* Wx   = (const float*)d_in[1];  // [2,2,512,2048] fp32
  const float* Wh   = (const float*)d_in[2];  // [2,2,512,2048] fp32
  const float* bias = (const float*)d_in[3];  // [2,2,2048] fp32

  u32* bar = (u32*)d_ws;
  ushort_t* ping = (ushort_t*)((char*)d_ws + 32768);

  hipFuncSetAttribute((const void*)bilstm_scan,
                      hipFuncAttributeMaxDynamicSharedMemorySize, SMEM_BYTES);

  // zero flag array + 12 h slots (ws is poisoned each call)
  hipMemsetAsync(d_ws, 0, 32768 + (size_t)12 * PING_ELEMS * sizeof(ushort_t), stream);

  hipLaunchKernelGGL(bilstm_scan, dim3(NBLK), dim3(THREADS), SMEM_BYTES, stream,
                     x, Wx, Wh, bias, ping, bar, (float*)d_out);
}

// Round 7
// 3258.393 us; speedup vs baseline: 5.0210x; 1.1703x over previous
//
#include <hip/hip_runtime.h>

typedef unsigned short ushort_t;
typedef unsigned int u32;
typedef unsigned long long u64;
typedef __attribute__((ext_vector_type(8))) short short8;   // 8 x bf16
typedef __attribute__((ext_vector_type(4))) float floatx4;  // MFMA acc / fp32x4

#define Tt 256
#define Hh 512
#define NBLK 256
#define THREADS 512
#define RWS 64             // batch rows per block
#define NIT 258            // 256 l0 steps + 2-interval lag drain for l1
#define PING_ELEMS 65536u  // 128*512 bf16 per hidden-state slot
#define KCH 256            // k per staged chunk
#define SLOT_SHORTS (RWS * KCH)                 // one LDS slot: 64 rows x 256 k
#define SMEM_BYTES (2*SLOT_SHORTS*2 + RWS*16*2 + RWS*16*4)  // 71680

__device__ __forceinline__ float sigf(float x)  { return 1.0f / (1.0f + __expf(-x)); }
__device__ __forceinline__ float tanhf_(float x){ return 1.0f - 2.0f / (__expf(2.0f*x) + 1.0f); }

// fp32 -> bf16 RNE
__device__ __forceinline__ ushort_t f2bf(float f) {
  u32 u = __float_as_uint(f);
  u += 0x7FFFu + ((u >> 16) & 1u);
  return (ushort_t)(u >> 16);
}

// device-coherence-point accesses for cross-block h traffic (bypass the
// non-coherent per-XCD L2). Row-strided dispersion kept (rounds 1-2 evidence).
__device__ __forceinline__ u64 pload(const ushort_t* p) {
  return __hip_atomic_load((const u64*)p, __ATOMIC_RELAXED, __HIP_MEMORY_SCOPE_AGENT);
}
__device__ __forceinline__ void pstore(ushort_t* p, u64 v) {
  __hip_atomic_store((u64*)p, v, __ATOMIC_RELAXED, __HIP_MEMORY_SCOPE_AGENT);
}
__device__ __forceinline__ u32 aload32(const u32* p) {
  return __hip_atomic_load(p, __ATOMIC_RELAXED, __HIP_MEMORY_SCOPE_AGENT);
}
__device__ __forceinline__ void astore32(u32* p, u32 v) {
  __hip_atomic_store(p, v, __ATOMIC_RELAXED, __HIP_MEMORY_SCOPE_AGENT);
}

// ---------------------------------------------------------------------------
// Round-6 structure (256 blocks row-split, 8 waves, register W^T, lane-local
// gates, register c-state, pre-barrier prestage of chunks 0,1 with l1 at
// lag 2 / depth-4 h0 ring, post-barrier own-h issue/commit pipeline; all
// access patterns, LDS layout/rotation, per-accumulator k-order unchanged ->
// identical absmax). This round, synchronization-scope surgery only:
//  * barrier groups shrink 128 -> 64 blocks: group = (d, nb). Dependency
//    graph is row-separable (own-h and h0 both come from same-(d,nb) blocks),
//    so cross-nb/cross-d coupling was pure overhead. 4 groups drift freely.
//  * split-phase barrier: ARRIVE (flag store) right after the stores-drained
//    __syncthreads, THEN prestage, THEN poll. Each block's prestage overlaps
//    all other blocks' arrival propagation. Max inter-block drift is 1
//    interval; ring WAR distances (2 slots in depth-4 ring) remain safe.
//  * 64 flags -> 1 flag/lane poll; final interval skips the dead barrier.
// ---------------------------------------------------------------------------
__global__ __launch_bounds__(THREADS, 2) void bilstm_scan(
    const float* __restrict__ x,     // [128][256][512] fp32
    const float* __restrict__ Wx,    // [2][2][512][2048] fp32
    const float* __restrict__ Wh,    // [2][2][512][2048] fp32
    const float* __restrict__ bias,  // [2][2][2048] fp32
    ushort_t* __restrict__ ping,     // 12 h slots (zeroed by memset)
    u32* __restrict__ barws,         // flag array (zeroed)
    float* __restrict__ out)         // [128][256][1024] fp32
{
  extern __shared__ __align__(16) char smem[];
  short* actb = (short*)smem;                                   // 2 x 32 KB
  ushort_t* hrep = (ushort_t*)(smem + 2 * SLOT_SHORTS * 2);     // 64x16 bf16
  float* hrep32 = (float*)(smem + 2 * SLOT_SHORTS * 2 + RWS*16*2);  // 64x16 f32

  const int blk = blockIdx.x;
  const int cb = blk & 31, nb = (blk >> 5) & 1, l = (blk >> 6) & 1, d = blk >> 7;
  const int rb0 = nb * RWS;
  const int fi = l * 32 + cb;                 // flag index within (d,nb) group
  const int tid = threadIdx.x;
  const int wvi = tid >> 6, lane = tid & 63;
  const int mw = wvi & 3, nw = wvi >> 2;      // m-tile, row-half (of 64)
  const int q = lane >> 4, ln = lane & 15;
  const int rl = tid >> 3, et = tid & 7;      // staging row (0..63) / eighth
  const int rot = (rl >> 1) & 31;             // LDS rotation for local row rl
  u32* flags = barws + (size_t)(d * 2 + nb) * 1024;  // 64 x 64B lines / group
  // per-direction h slots: ring[0..3] = l0 h (depth-4; doubles as l0's own
  // recurrence source), [4..5] = l1 own recurrence ping-pong. nb groups use
  // disjoint row ranges of each slot -> no cross-group hazard.
  ushort_t* dbase = ping + (size_t)d * 6 * PING_ELEMS;

  // zero LDS (staging holes -> finite-wrong, never NaN)
  for (int i = tid; i < (int)(SMEM_BYTES / 4); i += THREADS) ((u32*)smem)[i] = 0u;
  __syncthreads();

  // ---- W^T into registers (once), fp32 -> bf16. A-row ln of m-tile mw ->
  // gate-col (ln&3)*512 + cb*16 + mw*4 + (ln>>2); k = kc*32 + q*8 + j.
  short8 wreg[32];
  {
    const float* wxb = Wx + (size_t)(l * 2 + d) * 512 * 2048;
    const float* whb = Wh + (size_t)(l * 2 + d) * 512 * 2048;
    const int col = (ln & 3) * 512 + cb * 16 + mw * 4 + (ln >> 2);
#pragma unroll
    for (int kc = 0; kc < 32; ++kc) {
      union { short8 v; ushort_t u[8]; } tmp;
#pragma unroll
      for (int j2 = 0; j2 < 8; ++j2) {
        const int k = kc * 32 + q * 8 + j2;
        const float wv_ = (k < 512) ? wxb[(size_t)k * 2048 + col]
                                    : whb[(size_t)(k - 512) * 2048 + col];
        tmp.u[j2] = f2bf(wv_);
      }
      wreg[kc] = tmp.v;
    }
  }

  float brs[4];
  {
    const float* bp = bias + (size_t)(l * 2 + d) * 2048;
    const int j = cb * 16 + mw * 4 + q;
#pragma unroll
    for (int r = 0; r < 4; ++r) brs[r] = bp[r * 512 + j];
  }

  float cst[2];
  cst[0] = 0.f; cst[1] = 0.f;

  // ---- staging lambdas (LDS layout: local row rl, 16B unit u at
  // pos=(u+rot)&31; thread covers units et*4 .. et*4+3).
  auto x_prestage = [&](int tn) {   // l==0: stage x[tn] chunks 0,1
    const int tx = d ? (Tt - 1 - tn) : tn;
    const float* xf = x + (size_t)tx * Hh;
#pragma unroll
    for (int kc = 0; kc < 2; ++kc) {
      short* dst = actb + kc * SLOT_SHORTS;
      const float* s = xf + (size_t)(rb0 + rl) * ((size_t)Tt * Hh) + kc * KCH + et * 32;
#pragma unroll
      for (int uu = 0; uu < 4; ++uu) {
        floatx4 f0 = *(const floatx4*)(s + uu * 8);
        floatx4 f1 = *(const floatx4*)(s + uu * 8 + 4);
        union { uint4 v; ushort_t us[8]; } pk;
#pragma unroll
        for (int e = 0; e < 4; ++e) {
          pk.us[e] = f2bf(f0[e]);
          pk.us[4 + e] = f2bf(f1[e]);
        }
        const int pos = (et * 4 + uu + rot) & 31;
        *(uint4*)&dst[rl * KCH + pos * 8] = pk.v;
      }
    }
  };

  auto h0_prestage = [&](int tn) {  // l==1: stage h0[tn] chunks 0,1
    const ushort_t* h0 = dbase + (size_t)(tn & 3) * PING_ELEMS;
    const ushort_t* s = h0 + (size_t)(rb0 + rl) * Hh + et * 32;
    u64 g[8][2];
#pragma unroll
    for (int c = 0; c < 2; ++c)     // all 8 load pairs in flight at once
#pragma unroll
      for (int uu = 0; uu < 4; ++uu) {
        g[c * 4 + uu][0] = pload(s + c * 256 + uu * 8);
        g[c * 4 + uu][1] = pload(s + c * 256 + uu * 8 + 4);
      }
#pragma unroll
    for (int c = 0; c < 2; ++c) {
      short* dst = actb + c * SLOT_SHORTS;
#pragma unroll
      for (int uu = 0; uu < 4; ++uu) {
        uint4 v;
        v.x = (u32)g[c * 4 + uu][0]; v.y = (u32)(g[c * 4 + uu][0] >> 32);
        v.z = (u32)g[c * 4 + uu][1]; v.w = (u32)(g[c * 4 + uu][1] >> 32);
        const int pos = (et * 4 + uu + rot) & 31;
        *(uint4*)&dst[rl * KCH + pos * 8] = v;
      }
    }
  };

  // ---- bootstrap: prestage interval 0 (l0 only; l1 inactive until it=2)
  if (l == 0) x_prestage(0);

  for (int it = 0; it < NIT; ++it) {
    const bool active = (l == 0) ? (it < Tt) : (it >= 2);
    const int t = (l == 0) ? it : (it - 2);

    if (active) {
      // own h[t-1]: l0 from ring slot (t-1)&3; l1 from own ping-pong.
      const ushort_t* hp = (l == 0)
          ? dbase + (size_t)((t + 3) & 3) * PING_ELEMS
          : dbase + (size_t)(4 + (t & 1)) * PING_ELEMS;
      ushort_t* hdst = (l == 0)
          ? dbase + (size_t)(t & 3) * PING_ELEMS
          : dbase + (size_t)(4 + ((t + 1) & 1)) * PING_ELEMS;

      floatx4 acc[2];
      {
        floatx4 z4 = {0.f, 0.f, 0.f, 0.f};
        acc[0] = z4; acc[1] = z4;
      }

      u64 gA[4][2], gB[4][2];
      auto h_issue = [&](int kcol, u64 (&g)[4][2]) {
        const ushort_t* s = hp + (size_t)(rb0 + rl) * Hh + kcol + et * 32;
#pragma unroll
        for (int uu = 0; uu < 4; ++uu) {
          g[uu][0] = pload(s + uu * 8);
          g[uu][1] = pload(s + uu * 8 + 4);
        }
      };
      auto h_commit = [&](int kc, u64 (&g)[4][2]) {
        short* dst = actb + (kc & 1) * SLOT_SHORTS;
#pragma unroll
        for (int uu = 0; uu < 4; ++uu) {
          uint4 v;
          v.x = (u32)g[uu][0]; v.y = (u32)(g[uu][0] >> 32);
          v.z = (u32)g[uu][1]; v.w = (u32)(g[uu][1] >> 32);
          const int pos = (et * 4 + uu + rot) & 31;
          *(uint4*)&dst[rl * KCH + pos * 8] = v;
        }
      };
      auto compute = [&](int kc) {
        const short* src = actb + (kc & 1) * SLOT_SHORTS;
#pragma unroll
        for (int s = 0; s < 8; ++s) {
          short8 af[2];
#pragma unroll
          for (int nt = 0; nt < 2; ++nt) {
            const int b = nw * 32 + nt * 16 + ln;  // local row
            const int pos = (s * 4 + q + ((b >> 1) & 31)) & 31;
            af[nt] = *(const short8*)&src[b * KCH + pos * 8];
          }
          const int kidx = kc * 8 + s;
#pragma unroll
          for (int nt = 0; nt < 2; ++nt)
            acc[nt] = __builtin_amdgcn_mfma_f32_16x16x32_bf16(
                wreg[kidx], af[nt], acc[nt], 0, 0, 0);
        }
      };

      // ---- post-barrier pipeline: chunks 0,1 already in LDS (prestaged)
      h_issue(0, gA);                 // own-h loads in flight
      h_issue(256, gB);
      compute(0);
      __syncthreads();                // all done reading slot0
      h_commit(2, gA);
      compute(1);
      __syncthreads();                // slot0 committed; all done slot1 reads
      h_commit(3, gB);
      compute(2);
      __syncthreads();                // slot1 committed
      compute(3);

      // ---- cell math (lane-local), repack h via LDS for contiguous stores
      const int tout = d ? (Tt - 1 - t) : t;
      const int jj = mw * 4 + q;
#pragma unroll
      for (int nt = 0; nt < 2; ++nt) {
        const int b = nw * 32 + nt * 16 + ln;  // local row
        float iv = sigf  (acc[nt][0] + brs[0]);
        float fv = sigf  (acc[nt][1] + brs[1]);
        float gv = tanhf_(acc[nt][2] + brs[2]);
        float ov = sigf  (acc[nt][3] + brs[3]);
        float cv = fv * cst[nt] + iv * gv;
        cst[nt] = cv;
        float hv = ov * tanhf_(cv);
        hrep[b * 16 + jj] = f2bf(hv);
        if (l == 1) hrep32[b * 16 + jj] = hv;
      }
      __syncthreads();                // hrep ready; all slot reads done
      if (tid < 256) {
        const int rr = tid >> 2, qt = tid & 3;
        u64 hv64 = *(const u64*)&hrep[rr * 16 + qt * 4];
        ushort_t* dp = hdst + (size_t)(rb0 + rr) * Hh + cb * 16 + qt * 4;
        pstore(dp, hv64);
        if (l == 1) {
          float* op = out + ((size_t)(rb0 + rr) * Tt + tout) * 1024 + d * 512 + cb * 16 + qt * 4;
          *(floatx4*)op = *(const floatx4*)&hrep32[rr * 16 + qt * 4];
        }
      }
    }

    if (it == NIT - 1) break;   // no successor -> final barrier is dead

    // ---- ARRIVE: all waves' pstores drained by __syncthreads (compiler
    // emits per-wave vmcnt(0) before s_barrier) -> h[t] at coherence point.
    __syncthreads();
    const u32 target = (u32)(it + 1);
    if (tid == 0) astore32(flags + fi * 16, target);

    // ---- prestage chunks 0,1 for interval it+1 (overlaps other blocks'
    // arrival propagation; slots free: all reads done pre-ARRIVE)
    const bool nact = (l == 0) ? (it + 1 < Tt) : (it + 1 >= 2);
    if (nact) {
      if (l == 0) x_prestage(it + 1);
      else        h0_prestage(it - 1);   // t_next = (it+1)-2; ring slot (it-1)&3
    }

    // ---- WAIT: poll own group's 64 flags, 1 per lane
    if (tid < 64) {
      for (;;) {
        u32 a = aload32(flags + tid * 16);
        if (__all((int)(a >= target))) break;
        __builtin_amdgcn_s_sleep(1);
      }
    }
    asm volatile("" ::: "memory");
    __syncthreads();
  }
}

// ---------------------------------------------------------------------------
extern "C" void kernel_launch(void* const* d_in, const int* in_sizes, int n_in,
                              void* d_out, int out_size, void* d_ws, size_t ws_size,
                              hipStream_t stream) {
  const float* x    = (const float*)d_in[0];  // [128,256,512] fp32
  const float* Wx   = (const float*)d_in[1];  // [2,2,512,2048] fp32
  const float* Wh   = (const float*)d_in[2];  // [2,2,512,2048] fp32
  const float* bias = (const float*)d_in[3];  // [2,2,2048] fp32

  u32* bar = (u32*)d_ws;
  ushort_t* ping = (ushort_t*)((char*)d_ws + 32768);

  hipFuncSetAttribute((const void*)bilstm_scan,
                      hipFuncAttributeMaxDynamicSharedMemorySize, SMEM_BYTES);

  // zero flag array + 12 h slots (ws is poisoned each call)
  hipMemsetAsync(d_ws, 0, 32768 + (size_t)12 * PING_ELEMS * sizeof(ushort_t), stream);

  hipLaunchKernelGGL(bilstm_scan, dim3(NBLK), dim3(THREADS), SMEM_BYTES, stream,
                     x, Wx, Wh, bias, ping, bar, (float*)d_out);
}